// Round 1
// baseline (333.936 us; speedup 1.0000x reference)
//
#include <hip/hip_runtime.h>

typedef float v4f __attribute__((ext_vector_type(4)));

#define NB 8        // batch
#define NL 24       // layers
#define NR 64       // chunks
#define ND 4096     // DL
#define NFUSED 1536
#define NTF 1024
#define NPF 512
#define KT 18432    // DIM_T
#define KP 4096     // DP

// workspace float offsets
#define WS_FUSED 0          // 8*1536     = 12288
#define WS_GATE  12288      // 192
#define WS_FA    12480      // 8*4096     = 32768
#define WS_FB    45248      // 32768
#define WS_LA    78016      // 24*4096    = 98304
#define WS_LB    176320     // 98304
#define WS_CA    274624     // 64*4096    = 262144
#define WS_CBT   536768     // 262144
#define WS_PART  798912     // up to 72*8*1024 = 589824

// ---------------- t_feat = relu(flat_T @ W_ct + b_ct), split-K ----------------
// grid (4 jchunks, 72 kchunks), block 256
__global__ __launch_bounds__(256) void k_tfeat_partial(
    const float* __restrict__ As, const float* __restrict__ Bs,
    const float* __restrict__ W, float* __restrict__ part) {
  const int j = blockIdx.x * 256 + threadIdx.x;
  const int kbase = blockIdx.y * 256;
  float acc[NB] = {};
  for (int kk = 0; kk < 256; ++kk) {
    const int k = kbase + kk;
    const float w = W[(size_t)k * NTF + j];
    const float* x = (k < 9216) ? (As + k) : (Bs + (k - 9216));
#pragma unroll
    for (int b = 0; b < NB; ++b) acc[b] = fmaf(x[b * 9216], w, acc[b]);
  }
#pragma unroll
  for (int b = 0; b < NB; ++b)
    part[(size_t)(blockIdx.y * NB + b) * NTF + j] = acc[b];
}

// grid 32, block 256 over 8*1024
__global__ __launch_bounds__(256) void k_tfeat_reduce(
    const float* __restrict__ part, const float* __restrict__ bias,
    float* __restrict__ fused) {
  const int idx = blockIdx.x * 256 + threadIdx.x;
  const int b = idx >> 10, j = idx & 1023;
  float s = bias[j];
  for (int kc = 0; kc < 72; ++kc) s += part[(size_t)(kc * NB + b) * NTF + j];
  fused[b * NFUSED + j] = fmaxf(s, 0.f);
}

// ---------------- p_feat = relu(prompt @ W_cp + b_cp), split-K ----------------
// grid (2 jchunks, 16 kchunks), block 256
__global__ __launch_bounds__(256) void k_pfeat_partial(
    const float* __restrict__ P, const float* __restrict__ W,
    float* __restrict__ part) {
  const int j = blockIdx.x * 256 + threadIdx.x;
  const int kbase = blockIdx.y * 256;
  float acc[NB] = {};
  for (int kk = 0; kk < 256; ++kk) {
    const int k = kbase + kk;
    const float w = W[(size_t)k * NPF + j];
#pragma unroll
    for (int b = 0; b < NB; ++b) acc[b] = fmaf(P[b * KP + k], w, acc[b]);
  }
#pragma unroll
  for (int b = 0; b < NB; ++b)
    part[(size_t)(blockIdx.y * NB + b) * NPF + j] = acc[b];
}

// grid 16, block 256 over 8*512
__global__ __launch_bounds__(256) void k_pfeat_reduce(
    const float* __restrict__ part, const float* __restrict__ bias,
    float* __restrict__ fused) {
  const int idx = blockIdx.x * 256 + threadIdx.x;
  const int b = idx >> 9, j = idx & 511;
  float s = bias[j];
  for (int kc = 0; kc < 16; ++kc) s += part[(size_t)(kc * NB + b) * NPF + j];
  fused[b * NFUSED + NTF + j] = fmaxf(s, 0.f);
}

// ---------------- gate: (fused @ W_pc + b_pc) > 0 ----------------
// grid 192, block 64 (one wave per (b,l))
__global__ __launch_bounds__(64) void k_gate(
    const float* __restrict__ fused, const float* __restrict__ W,
    const float* __restrict__ bias, float* __restrict__ gate_ws,
    float* __restrict__ gate_out) {
  const int bl = blockIdx.x;
  const int b = bl / NL, l = bl % NL;
  const int lane = threadIdx.x;
  float s = 0.f;
  for (int k = lane; k < NFUSED; k += 64)
    s = fmaf(fused[b * NFUSED + k], W[k * NL + l], s);
#pragma unroll
  for (int off = 32; off > 0; off >>= 1) s += __shfl_down(s, off);
  if (lane == 0) {
    const float g = (s + bias[l]) > 0.f ? 1.f : 0.f;
    gate_ws[bl] = g;
    gate_out[bl] = g;
  }
}

// ---------------- F = fused @ W[0:1536,:] (+bias at reduce), split-K ----------
// grid (16 dchunks, 6 kchunks), block 256
__global__ __launch_bounds__(256) void k_F_partial(
    const float* __restrict__ fused, const float* __restrict__ W,
    float* __restrict__ part) {
  const int d = blockIdx.x * 256 + threadIdx.x;
  const int kbase = blockIdx.y * 256;
  float acc[NB] = {};
  for (int kk = 0; kk < 256; ++kk) {
    const int k = kbase + kk;
    const float w = W[(size_t)k * ND + d];
#pragma unroll
    for (int b = 0; b < NB; ++b) acc[b] = fmaf(fused[b * NFUSED + k], w, acc[b]);
  }
#pragma unroll
  for (int b = 0; b < NB; ++b)
    part[(size_t)(blockIdx.y * NB + b) * ND + d] = acc[b];
}

// grid 128, block 256 over 8*4096
__global__ __launch_bounds__(256) void k_F_reduce(
    const float* __restrict__ part, const float* __restrict__ bias,
    float* __restrict__ F) {
  const int idx = blockIdx.x * 256 + threadIdx.x;
  const int b = idx >> 12, d = idx & 4095;
  float s = bias[d];
  for (int kc = 0; kc < 6; ++kc) s += part[(size_t)(kc * NB + b) * ND + d];
  F[idx] = s;
}

// ---------------- L = E_layer @ W[1536:1792,:] ----------------
// grid (16 dchunks, 4 lquads), block 256
__global__ __launch_bounds__(256) void k_L(
    const float* __restrict__ E, const float* __restrict__ W,
    float* __restrict__ Lout) {
  const int d = blockIdx.x * 256 + threadIdx.x;
  const int l0 = blockIdx.y * 6;
  float acc[6] = {};
  for (int k = 0; k < 256; ++k) {
    const float w = W[(size_t)k * ND + d];
#pragma unroll
    for (int i = 0; i < 6; ++i) acc[i] = fmaf(E[(l0 + i) * 256 + k], w, acc[i]);
  }
#pragma unroll
  for (int i = 0; i < 6; ++i) Lout[(size_t)(l0 + i) * ND + d] = acc[i];
}

// ---------------- C = E_chunk @ W[1792:1856,:] ----------------
// grid 16, block 256. Cout in [r][d]; CTout in [d][r] (either may be null)
__global__ __launch_bounds__(256) void k_C(
    const float* __restrict__ E, const float* __restrict__ W,
    float* __restrict__ Cout, float* __restrict__ CTout) {
  __shared__ float e[NR * 64];
  for (int i = threadIdx.x; i < NR * 64; i += 256) e[i] = E[i];
  __syncthreads();
  const int d = blockIdx.x * 256 + threadIdx.x;
  float w[64];
#pragma unroll
  for (int k = 0; k < 64; ++k) w[k] = W[(size_t)k * ND + d];
  for (int r = 0; r < NR; ++r) {
    float s = 0.f;
#pragma unroll
    for (int k = 0; k < 64; ++k) s = fmaf(e[r * 64 + k], w[k], s);
    if (Cout)  Cout[(size_t)r * ND + d] = s;
    if (CTout) CTout[(size_t)d * NR + r] = s;
  }
}

// ---------------- A_large writer ----------------
// grid (192, 4 dchunks, 2 rchunks), block 256
__global__ __launch_bounds__(256) void k_outA(
    const float* __restrict__ FA, const float* __restrict__ LA,
    const float* __restrict__ CA, const float* __restrict__ gate,
    float* __restrict__ out) {
  const int bl = blockIdx.x;
  const int b = bl / NL, l = bl % NL;
  const int d = blockIdx.y * 1024 + threadIdx.x * 4;
  const int r0 = blockIdx.z * 32;
  const float g = gate[bl];
  const v4f fa = *(const v4f*)(FA + (size_t)b * ND + d);
  const v4f la = *(const v4f*)(LA + (size_t)l * ND + d);
  const v4f base = fa + la;
  float* outp = out + ((size_t)bl * NR + r0) * ND + d;
  for (int r = 0; r < 32; ++r) {
    const v4f c = *(const v4f*)(CA + (size_t)(r0 + r) * ND + d);
    const v4f v = (base + c) * g;
    __builtin_nontemporal_store(v, (v4f*)outp);
    outp += ND;
  }
}

// ---------------- B_large writer (transposed) ----------------
// grid (192, 8 dchunks), block 256
__global__ __launch_bounds__(256) void k_outB(
    const float* __restrict__ FB, const float* __restrict__ LB,
    const float* __restrict__ CBT, float* __restrict__ out) {
  const int bl = blockIdx.x;
  const int b = bl / NL, l = bl % NL;
  const int dd = threadIdx.x >> 4;
  const int r4 = (threadIdx.x & 15) * 4;
  const int dbase = blockIdx.y * 512;
  for (int i = 0; i < 32; ++i) {
    const int d = dbase + i * 16 + dd;
    const float base = FB[(size_t)b * ND + d] + LB[(size_t)l * ND + d];
    const v4f c = *(const v4f*)(CBT + (size_t)d * NR + r4);
    const v4f v = c + base;
    __builtin_nontemporal_store(v, (v4f*)(out + ((size_t)bl * ND + d) * NR + r4));
  }
}

extern "C" void kernel_launch(void* const* d_in, const int* in_sizes, int n_in,
                              void* d_out, int out_size, void* d_ws, size_t ws_size,
                              hipStream_t stream) {
  const float* A_small   = (const float*)d_in[0];
  const float* B_small   = (const float*)d_in[1];
  const float* prompt    = (const float*)d_in[2];
  const float* W_ct      = (const float*)d_in[3];
  const float* b_ct      = (const float*)d_in[4];
  const float* W_cp      = (const float*)d_in[5];
  const float* b_cp      = (const float*)d_in[6];
  const float* W_pc      = (const float*)d_in[7];
  const float* b_pc      = (const float*)d_in[8];
  const float* E_layer   = (const float*)d_in[9];
  const float* E_chunk   = (const float*)d_in[10];
  const float* W_A       = (const float*)d_in[11];
  const float* b_A       = (const float*)d_in[12];
  const float* W_B       = (const float*)d_in[13];
  const float* b_B       = (const float*)d_in[14];

  float* ws    = (float*)d_ws;
  float* fused = ws + WS_FUSED;
  float* gatew = ws + WS_GATE;
  float* FA    = ws + WS_FA;
  float* FB    = ws + WS_FB;
  float* LA    = ws + WS_LA;
  float* LB    = ws + WS_LB;
  float* CA    = ws + WS_CA;
  float* CBT   = ws + WS_CBT;
  float* part  = ws + WS_PART;

  float* outA = (float*)d_out;                       // [192,64,4096]
  float* outB = outA + (size_t)192 * NR * ND;        // [192,4096,64]
  float* outG = outB + (size_t)192 * ND * NR;        // [192]

  // fused features
  k_tfeat_partial<<<dim3(4, 72), 256, 0, stream>>>(A_small, B_small, W_ct, part);
  k_tfeat_reduce<<<32, 256, 0, stream>>>(part, b_ct, fused);
  k_pfeat_partial<<<dim3(2, 16), 256, 0, stream>>>(prompt, W_cp, part);
  k_pfeat_reduce<<<16, 256, 0, stream>>>(part, b_cp, fused);

  // gate
  k_gate<<<192, 64, 0, stream>>>(fused, W_pc, b_pc, gatew, outG);

  // F terms (fused part of W_A / W_B) + bias
  k_F_partial<<<dim3(16, 6), 256, 0, stream>>>(fused, W_A, part);
  k_F_reduce<<<128, 256, 0, stream>>>(part, b_A, FA);
  k_F_partial<<<dim3(16, 6), 256, 0, stream>>>(fused, W_B, part);
  k_F_reduce<<<128, 256, 0, stream>>>(part, b_B, FB);

  // L terms (E_layer part)
  k_L<<<dim3(16, 4), 256, 0, stream>>>(E_layer, W_A + (size_t)NFUSED * ND, LA);
  k_L<<<dim3(16, 4), 256, 0, stream>>>(E_layer, W_B + (size_t)NFUSED * ND, LB);

  // C terms (E_chunk part)
  k_C<<<16, 256, 0, stream>>>(E_chunk, W_A + (size_t)(NFUSED + 256) * ND, CA, nullptr);
  k_C<<<16, 256, 0, stream>>>(E_chunk, W_B + (size_t)(NFUSED + 256) * ND, nullptr, CBT);

  // outputs
  k_outA<<<dim3(192, 4, 2), 256, 0, stream>>>(FA, LA, CA, gatew, outA);
  k_outB<<<dim3(192, 8), 256, 0, stream>>>(FB, LB, CBT, outB);
}

// Round 2
// 154.012 us; speedup vs baseline: 2.1682x; 2.1682x over previous
//
#include <hip/hip_runtime.h>

typedef float v4f __attribute__((ext_vector_type(4)));

#define NB 8        // batch
#define NL 24       // layers
#define NR 64       // chunks
#define ND 4096     // DL
#define NFUSED 1536
#define NTF 1024
#define NPF 512
#define KT 18432    // DIM_T
#define KP 4096     // DP

// workspace float offsets
#define WS_FUSED 0          // 12288
#define WS_GATE  12288      // 192
#define WS_LA    12480      // 98304
#define WS_LB    110784     // 98304
#define WS_CA    209088     // 262144
#define WS_CBT   471232     // 262144
#define WS_PT    733376     // 72*8*1024 = 589824
#define WS_PP    1323200    // 16*8*512  = 65536
#define WS_PFA   1388736    // 6*8*4096  = 196608
#define WS_PFB   1585344    // 196608  (end 1781952)

// =====================================================================
// K1: everything independent of `fused` — one launch, 480 blocks.
//   [0,288)   tfeat partials   (4 j-chunks x 72 k-chunks)
//   [288,320) pfeat partials   (2 j-chunks x 16 k-chunks)
//   [320,384) L_A              (16 d-chunks x 4 l-quads)
//   [384,448) L_B
//   [448,464) C_A   (16 d-chunks)
//   [464,480) C_BT  (16 d-chunks)
// =====================================================================
__global__ __launch_bounds__(256) void k_indep(
    const float* __restrict__ As, const float* __restrict__ Bs,
    const float* __restrict__ W_ct,
    const float* __restrict__ prompt, const float* __restrict__ W_cp,
    const float* __restrict__ E_layer, const float* __restrict__ E_chunk,
    const float* __restrict__ W_A, const float* __restrict__ W_B,
    float* __restrict__ partT, float* __restrict__ partP,
    float* __restrict__ LA, float* __restrict__ LB,
    float* __restrict__ CA, float* __restrict__ CBT) {
  __shared__ float e[NR * 64];
  const int bx = blockIdx.x;
  const int tid = threadIdx.x;

  if (bx < 288) {                       // ---- tfeat partial
    const int j = (bx & 3) * 256 + tid;
    const int kbase = (bx >> 2) * 256;
    float acc[NB] = {};
    for (int kk = 0; kk < 256; ++kk) {
      const int k = kbase + kk;
      const float w = W_ct[(size_t)k * NTF + j];
      const float* x = (k < 9216) ? (As + k) : (Bs + (k - 9216));
#pragma unroll
      for (int b = 0; b < NB; ++b) acc[b] = fmaf(x[b * 9216], w, acc[b]);
    }
#pragma unroll
    for (int b = 0; b < NB; ++b)
      partT[(size_t)((bx >> 2) * NB + b) * NTF + j] = acc[b];
  } else if (bx < 320) {                // ---- pfeat partial
    const int t = bx - 288;
    const int j = (t & 1) * 256 + tid;
    const int kbase = (t >> 1) * 256;
    float acc[NB] = {};
    for (int kk = 0; kk < 256; ++kk) {
      const int k = kbase + kk;
      const float w = W_cp[(size_t)k * NPF + j];
#pragma unroll
      for (int b = 0; b < NB; ++b) acc[b] = fmaf(prompt[b * KP + k], w, acc[b]);
    }
#pragma unroll
    for (int b = 0; b < NB; ++b)
      partP[(size_t)((t >> 1) * NB + b) * NPF + j] = acc[b];
  } else if (bx < 448) {                // ---- L_A / L_B
    const int t = bx - 320;
    const bool isA = t < 64;
    const int tt = isA ? t : t - 64;
    const float* W = (isA ? W_A : W_B) + (size_t)NFUSED * ND;
    float* Lout = isA ? LA : LB;
    const int d = (tt & 15) * 256 + tid;
    const int l0 = (tt >> 4) * 6;
    float acc[6] = {};
    for (int k = 0; k < 256; ++k) {
      const float w = W[(size_t)k * ND + d];
#pragma unroll
      for (int i = 0; i < 6; ++i) acc[i] = fmaf(E_layer[(l0 + i) * 256 + k], w, acc[i]);
    }
#pragma unroll
    for (int i = 0; i < 6; ++i) Lout[(size_t)(l0 + i) * ND + d] = acc[i];
  } else {                              // ---- C_A / C_BT
    const int t = bx - 448;
    const bool isA = t < 16;
    const int tt = isA ? t : t - 16;
    const float* W = (isA ? W_A : W_B) + (size_t)(NFUSED + 256) * ND;
    for (int i = tid; i < NR * 64; i += 256) e[i] = E_chunk[i];
    __syncthreads();
    const int d = tt * 256 + tid;
    float w[64];
#pragma unroll
    for (int k = 0; k < 64; ++k) w[k] = W[(size_t)k * ND + d];
    for (int r = 0; r < NR; ++r) {
      float s = 0.f;
#pragma unroll
      for (int k = 0; k < 64; ++k) s = fmaf(e[r * 64 + k], w[k], s);
      if (isA) CA[(size_t)r * ND + d] = s;
      else     CBT[(size_t)d * NR + r] = s;
    }
  }
}

// =====================================================================
// K2: fused reduce — 48 blocks ([0,32) tfeat, [32,48) pfeat)
// =====================================================================
__global__ __launch_bounds__(256) void k_fused_reduce(
    const float* __restrict__ partT, const float* __restrict__ partP,
    const float* __restrict__ b_ct, const float* __restrict__ b_cp,
    float* __restrict__ fused) {
  const int bx = blockIdx.x;
  if (bx < 32) {
    const int idx = bx * 256 + threadIdx.x;
    const int b = idx >> 10, j = idx & 1023;
    float s = b_ct[j];
    for (int kc = 0; kc < 72; ++kc) s += partT[(size_t)(kc * NB + b) * NTF + j];
    fused[b * NFUSED + j] = fmaxf(s, 0.f);
  } else {
    const int idx = (bx - 32) * 256 + threadIdx.x;
    const int b = idx >> 9, j = idx & 511;
    float s = b_cp[j];
    for (int kc = 0; kc < 16; ++kc) s += partP[(size_t)(kc * NB + b) * NPF + j];
    fused[b * NFUSED + NTF + j] = fmaxf(s, 0.f);
  }
}

// =====================================================================
// K3: F_A / F_B split-K partials + gate — 384 blocks
//   [0,96)   F_A partial (16 d-chunks x 6 k-chunks)
//   [96,192) F_B partial
//   [192,384) gate, one (b,l) per block
// =====================================================================
__global__ __launch_bounds__(256) void k_dep(
    const float* __restrict__ fused,
    const float* __restrict__ W_A, const float* __restrict__ W_B,
    const float* __restrict__ W_pc, const float* __restrict__ b_pc,
    float* __restrict__ pFA, float* __restrict__ pFB,
    float* __restrict__ gate_ws, float* __restrict__ gate_out) {
  __shared__ float red[256];
  const int bx = blockIdx.x;
  const int tid = threadIdx.x;
  if (bx < 192) {
    const bool isA = bx < 96;
    const int t = isA ? bx : bx - 96;
    const float* W = isA ? W_A : W_B;
    float* part = isA ? pFA : pFB;
    const int d = (t & 15) * 256 + tid;
    const int kbase = (t >> 4) * 256;
    float acc[NB] = {};
    for (int kk = 0; kk < 256; ++kk) {
      const int k = kbase + kk;
      const float w = W[(size_t)k * ND + d];
#pragma unroll
      for (int b = 0; b < NB; ++b) acc[b] = fmaf(fused[b * NFUSED + k], w, acc[b]);
    }
#pragma unroll
    for (int b = 0; b < NB; ++b)
      part[(size_t)((t >> 4) * NB + b) * ND + d] = acc[b];
  } else {
    const int bl = bx - 192;
    const int b = bl / NL, l = bl % NL;
    float s = 0.f;
    for (int k = tid; k < NFUSED; k += 256)
      s = fmaf(fused[b * NFUSED + k], W_pc[k * NL + l], s);
    red[tid] = s;
    __syncthreads();
#pragma unroll
    for (int off = 128; off > 0; off >>= 1) {
      if (tid < off) red[tid] += red[tid + off];
      __syncthreads();
    }
    if (tid == 0) {
      const float g = (red[0] + b_pc[l]) > 0.f ? 1.f : 0.f;
      gate_ws[bl] = g;
      gate_out[bl] = g;
    }
  }
}

// =====================================================================
// K4: writers (F-reduce folded in) — 3072 blocks
//   [0,1536)    A_large: bl = t>>3, dchunk = (t&7)>>1, rchunk = t&1
//   [1536,3072) B_large: bl = t>>3, dchunk = t&7
// =====================================================================
__global__ __launch_bounds__(256) void k_out(
    const float* __restrict__ pFA, const float* __restrict__ pFB,
    const float* __restrict__ b_A, const float* __restrict__ b_B,
    const float* __restrict__ LA, const float* __restrict__ LB,
    const float* __restrict__ CA, const float* __restrict__ CBT,
    const float* __restrict__ gate,
    float* __restrict__ outA, float* __restrict__ outB) {
  __shared__ float sbase[512];
  const int bx = blockIdx.x;
  const int tid = threadIdx.x;
  if (bx < 1536) {                      // ---- A writer
    const int bl = bx >> 3;
    const int rest = bx & 7;
    const int b = bl / NL, l = bl % NL;
    const int d = (rest >> 1) * 1024 + tid * 4;
    const int r0 = (rest & 1) * 32;
    const float g = gate[bl];
    v4f base = *(const v4f*)(b_A + d);
#pragma unroll
    for (int kc = 0; kc < 6; ++kc)
      base += *(const v4f*)(pFA + (size_t)(kc * NB + b) * ND + d);
    base += *(const v4f*)(LA + (size_t)l * ND + d);
    float* outp = outA + ((size_t)bl * NR + r0) * ND + d;
    for (int r = 0; r < 32; ++r) {
      const v4f c = *(const v4f*)(CA + (size_t)(r0 + r) * ND + d);
      const v4f v = (base + c) * g;
      __builtin_nontemporal_store(v, (v4f*)outp);
      outp += ND;
    }
  } else {                              // ---- B writer
    const int t = bx - 1536;
    const int bl = t >> 3;
    const int b = bl / NL, l = bl % NL;
    const int dbase = (t & 7) * 512;
    for (int dd = tid; dd < 512; dd += 256) {
      const int d = dbase + dd;
      float s = b_B[d] + LB[(size_t)l * ND + d];
#pragma unroll
      for (int kc = 0; kc < 6; ++kc)
        s += pFB[(size_t)(kc * NB + b) * ND + d];
      sbase[dd] = s;
    }
    __syncthreads();
    const int dd16 = tid >> 4;
    const int r4 = (tid & 15) * 4;
    for (int i = 0; i < 32; ++i) {
      const int dloc = i * 16 + dd16;
      const int d = dbase + dloc;
      const v4f c = *(const v4f*)(CBT + (size_t)d * NR + r4);
      const v4f v = c + sbase[dloc];
      __builtin_nontemporal_store(v, (v4f*)(outB + ((size_t)bl * ND + d) * NR + r4));
    }
  }
}

extern "C" void kernel_launch(void* const* d_in, const int* in_sizes, int n_in,
                              void* d_out, int out_size, void* d_ws, size_t ws_size,
                              hipStream_t stream) {
  const float* A_small   = (const float*)d_in[0];
  const float* B_small   = (const float*)d_in[1];
  const float* prompt    = (const float*)d_in[2];
  const float* W_ct      = (const float*)d_in[3];
  const float* b_ct      = (const float*)d_in[4];
  const float* W_cp      = (const float*)d_in[5];
  const float* b_cp      = (const float*)d_in[6];
  const float* W_pc      = (const float*)d_in[7];
  const float* b_pc      = (const float*)d_in[8];
  const float* E_layer   = (const float*)d_in[9];
  const float* E_chunk   = (const float*)d_in[10];
  const float* W_A       = (const float*)d_in[11];
  const float* b_A       = (const float*)d_in[12];
  const float* W_B       = (const float*)d_in[13];
  const float* b_B       = (const float*)d_in[14];

  float* ws    = (float*)d_ws;
  float* fused = ws + WS_FUSED;
  float* gatew = ws + WS_GATE;
  float* LA    = ws + WS_LA;
  float* LB    = ws + WS_LB;
  float* CA    = ws + WS_CA;
  float* CBT   = ws + WS_CBT;
  float* partT = ws + WS_PT;
  float* partP = ws + WS_PP;
  float* pFA   = ws + WS_PFA;
  float* pFB   = ws + WS_PFB;

  float* outA = (float*)d_out;                       // [192,64,4096]
  float* outB = outA + (size_t)192 * NR * ND;        // [192,4096,64]
  float* outG = outB + (size_t)192 * ND * NR;        // [192]

  k_indep<<<480, 256, 0, stream>>>(A_small, B_small, W_ct, prompt, W_cp,
                                   E_layer, E_chunk, W_A, W_B,
                                   partT, partP, LA, LB, CA, CBT);
  k_fused_reduce<<<48, 256, 0, stream>>>(partT, partP, b_ct, b_cp, fused);
  k_dep<<<384, 256, 0, stream>>>(fused, W_A, W_B, W_pc, b_pc,
                                 pFA, pFB, gatew, outG);
  k_out<<<3072, 256, 0, stream>>>(pFA, pFB, b_A, b_B, LA, LB, CA, CBT,
                                  gatew, outA, outB);
}

// Round 3
// 151.492 us; speedup vs baseline: 2.2043x; 1.0166x over previous
//
#include <hip/hip_runtime.h>

typedef float v4f __attribute__((ext_vector_type(4)));

#define NB 8        // batch
#define NL 24       // layers
#define NR 64       // chunks
#define ND 4096     // DL
#define NFUSED 1536
#define NTF 1024
#define NPF 512
#define KP 4096     // DP

// split-K chunking
#define TKC 144     // tfeat k-chunks of 128 (18432/128)
#define PKC 32      // pfeat k-chunks of 128 (4096/128)
#define FKC 12      // F k-chunks of 128 (1536/128)

// workspace float offsets
#define WS_FUSED 0          // 12288
#define WS_GATE  12288      // 192                -> 12480
#define WS_PLA   12480      // 2*24*4096 = 196608 -> 209088
#define WS_PLB   209088     // 196608             -> 405696
#define WS_CA    405696     // 262144             -> 667840
#define WS_CBT   667840     // 262144             -> 929984
#define WS_PT    929984     // 144*8*1024=1179648 -> 2109632
#define WS_PP    2109632    // 32*8*512 = 131072  -> 2240704
#define WS_PFA   2240704    // 12*8*4096= 393216  -> 2633920
#define WS_PFB   2633920    // 393216             -> 3027136

// =====================================================================
// K1: everything independent of `fused` — 736 blocks, ~128KB read each.
//   [0,576)   tfeat partials   (4 j-chunks x 144 k-chunks of 128)
//   [576,640) pfeat partials   (2 j-chunks x 32 k-chunks of 128)
//   [640,704) L_A / L_B        (16 d-chunks x 2 k-halves x 2 mats)
//   [704,736) C_A / C_BT       (16 d-chunks x 2 mats)
// =====================================================================
__global__ __launch_bounds__(256) void k_indep(
    const float* __restrict__ As, const float* __restrict__ Bs,
    const float* __restrict__ W_ct,
    const float* __restrict__ prompt, const float* __restrict__ W_cp,
    const float* __restrict__ E_layer, const float* __restrict__ E_chunk,
    const float* __restrict__ W_A, const float* __restrict__ W_B,
    float* __restrict__ partT, float* __restrict__ partP,
    float* __restrict__ pLA, float* __restrict__ pLB,
    float* __restrict__ CA, float* __restrict__ CBT) {
  __shared__ float e[NR * 64];
  const int bx = blockIdx.x;
  const int tid = threadIdx.x;

  if (bx < 576) {                       // ---- tfeat partial (k-chunk 128)
    const int j = (bx & 3) * 256 + tid;
    const int kc = bx >> 2;
    const int kbase = kc * 128;
    float acc[NB] = {};
    for (int kk = 0; kk < 128; ++kk) {
      const int k = kbase + kk;
      const float w = W_ct[(size_t)k * NTF + j];
      const float* x = (k < 9216) ? (As + k) : (Bs + (k - 9216));
#pragma unroll
      for (int b = 0; b < NB; ++b) acc[b] = fmaf(x[b * 9216], w, acc[b]);
    }
#pragma unroll
    for (int b = 0; b < NB; ++b)
      partT[(size_t)(kc * NB + b) * NTF + j] = acc[b];
  } else if (bx < 640) {                // ---- pfeat partial (k-chunk 128)
    const int t = bx - 576;
    const int j = (t & 1) * 256 + tid;
    const int kc = t >> 1;
    const int kbase = kc * 128;
    float acc[NB] = {};
    for (int kk = 0; kk < 128; ++kk) {
      const int k = kbase + kk;
      const float w = W_cp[(size_t)k * NPF + j];
#pragma unroll
      for (int b = 0; b < NB; ++b) acc[b] = fmaf(prompt[b * KP + k], w, acc[b]);
    }
#pragma unroll
    for (int b = 0; b < NB; ++b)
      partP[(size_t)(kc * NB + b) * NPF + j] = acc[b];
  } else if (bx < 704) {                // ---- L_A / L_B (split-K 2 halves)
    const int t = bx - 640;
    const bool isA = t < 32;
    const int tt = isA ? t : t - 32;
    const int dc = tt & 15;
    const int kh = tt >> 4;             // 0 or 1
    const float* W = (isA ? W_A : W_B) + (size_t)(NFUSED + kh * 128) * ND;
    float* pL = (isA ? pLA : pLB) + (size_t)kh * NL * ND;
    const int d = dc * 256 + tid;
    float acc[NL] = {};
    for (int kk = 0; kk < 128; ++kk) {
      const float w = W[(size_t)kk * ND + d];
      const float* el = E_layer + kh * 128 + kk;
#pragma unroll
      for (int l = 0; l < NL; ++l) acc[l] = fmaf(el[l * 256], w, acc[l]);
    }
#pragma unroll
    for (int l = 0; l < NL; ++l) pL[(size_t)l * ND + d] = acc[l];
  } else {                              // ---- C_A / C_BT
    const int t = bx - 704;
    const bool isA = t < 16;
    const int tt = isA ? t : t - 16;
    const float* W = (isA ? W_A : W_B) + (size_t)(NFUSED + 256) * ND;
    for (int i = tid; i < NR * 64; i += 256) e[i] = E_chunk[i];
    __syncthreads();
    const int d = tt * 256 + tid;
    float w[64];
#pragma unroll
    for (int k = 0; k < 64; ++k) w[k] = W[(size_t)k * ND + d];
    for (int r = 0; r < NR; ++r) {
      float s = 0.f;
#pragma unroll
      for (int k = 0; k < 64; ++k) s = fmaf(e[r * 64 + k], w[k], s);
      if (isA) CA[(size_t)r * ND + d] = s;
      else     CBT[(size_t)d * NR + r] = s;
    }
  }
}

// =====================================================================
// K2: fused reduce — 48 blocks ([0,32) tfeat, [32,48) pfeat)
// =====================================================================
__global__ __launch_bounds__(256) void k_fused_reduce(
    const float* __restrict__ partT, const float* __restrict__ partP,
    const float* __restrict__ b_ct, const float* __restrict__ b_cp,
    float* __restrict__ fused) {
  const int bx = blockIdx.x;
  if (bx < 32) {
    const int idx = bx * 256 + threadIdx.x;
    const int b = idx >> 10, j = idx & 1023;
    float s = b_ct[j];
    for (int kc = 0; kc < TKC; ++kc) s += partT[(size_t)(kc * NB + b) * NTF + j];
    fused[b * NFUSED + j] = fmaxf(s, 0.f);
  } else {
    const int idx = (bx - 32) * 256 + threadIdx.x;
    const int b = idx >> 9, j = idx & 511;
    float s = b_cp[j];
    for (int kc = 0; kc < PKC; ++kc) s += partP[(size_t)(kc * NB + b) * NPF + j];
    fused[b * NFUSED + NTF + j] = fmaxf(s, 0.f);
  }
}

// =====================================================================
// K3: F_A / F_B split-K partials (k-chunk 128) + gate — 576 blocks
//   [0,192)   F_A partial (16 d-chunks x 12 k-chunks)
//   [192,384) F_B partial
//   [384,576) gate, one (b,l) per block
// =====================================================================
__global__ __launch_bounds__(256) void k_dep(
    const float* __restrict__ fused,
    const float* __restrict__ W_A, const float* __restrict__ W_B,
    const float* __restrict__ W_pc, const float* __restrict__ b_pc,
    float* __restrict__ pFA, float* __restrict__ pFB,
    float* __restrict__ gate_ws, float* __restrict__ gate_out) {
  __shared__ float red[256];
  const int bx = blockIdx.x;
  const int tid = threadIdx.x;
  if (bx < 384) {
    const bool isA = bx < 192;
    const int t = isA ? bx : bx - 192;
    const float* W = isA ? W_A : W_B;
    float* part = isA ? pFA : pFB;
    const int d = (t & 15) * 256 + tid;
    const int kc = t >> 4;
    const int kbase = kc * 128;
    float acc[NB] = {};
    for (int kk = 0; kk < 128; ++kk) {
      const int k = kbase + kk;
      const float w = W[(size_t)k * ND + d];
#pragma unroll
      for (int b = 0; b < NB; ++b) acc[b] = fmaf(fused[b * NFUSED + k], w, acc[b]);
    }
#pragma unroll
    for (int b = 0; b < NB; ++b)
      part[(size_t)(kc * NB + b) * ND + d] = acc[b];
  } else {
    const int bl = bx - 384;
    const int b = bl / NL, l = bl % NL;
    float s = 0.f;
    for (int k = tid; k < NFUSED; k += 256)
      s = fmaf(fused[b * NFUSED + k], W_pc[k * NL + l], s);
    red[tid] = s;
    __syncthreads();
#pragma unroll
    for (int off = 128; off > 0; off >>= 1) {
      if (tid < off) red[tid] += red[tid + off];
      __syncthreads();
    }
    if (tid == 0) {
      const float g = (red[0] + b_pc[l]) > 0.f ? 1.f : 0.f;
      gate_ws[bl] = g;
      gate_out[bl] = g;
    }
  }
}

// =====================================================================
// K4: writers (F-reduce + L-reduce folded in) — 3072 blocks
//   [0,1536)    A_large: bl = t>>3, dchunk = (t&7)>>1, rchunk = t&1
//   [1536,3072) B_large: bl = t>>3, dchunk = t&7
// =====================================================================
__global__ __launch_bounds__(256) void k_out(
    const float* __restrict__ pFA, const float* __restrict__ pFB,
    const float* __restrict__ b_A, const float* __restrict__ b_B,
    const float* __restrict__ pLA, const float* __restrict__ pLB,
    const float* __restrict__ CA, const float* __restrict__ CBT,
    const float* __restrict__ gate,
    float* __restrict__ outA, float* __restrict__ outB) {
  __shared__ float sbase[512];
  const int bx = blockIdx.x;
  const int tid = threadIdx.x;
  if (bx < 1536) {                      // ---- A writer
    const int bl = bx >> 3;
    const int rest = bx & 7;
    const int b = bl / NL, l = bl % NL;
    const int d = (rest >> 1) * 1024 + tid * 4;
    const int r0 = (rest & 1) * 32;
    const float g = gate[bl];
    v4f base = *(const v4f*)(b_A + d);
#pragma unroll
    for (int kc = 0; kc < FKC; ++kc)
      base += *(const v4f*)(pFA + (size_t)(kc * NB + b) * ND + d);
    base += *(const v4f*)(pLA + (size_t)l * ND + d);
    base += *(const v4f*)(pLA + (size_t)(NL + l) * ND + d);
    float* outp = outA + ((size_t)bl * NR + r0) * ND + d;
#pragma unroll 4
    for (int r = 0; r < 32; ++r) {
      const v4f c = *(const v4f*)(CA + (size_t)(r0 + r) * ND + d);
      const v4f v = (base + c) * g;
      __builtin_nontemporal_store(v, (v4f*)outp);
      outp += ND;
    }
  } else {                              // ---- B writer
    const int t = bx - 1536;
    const int bl = t >> 3;
    const int b = bl / NL, l = bl % NL;
    const int dbase = (t & 7) * 512;
    for (int dd = tid; dd < 512; dd += 256) {
      const int d = dbase + dd;
      float s = b_B[d] + pLB[(size_t)l * ND + d] + pLB[(size_t)(NL + l) * ND + d];
#pragma unroll
      for (int kc = 0; kc < FKC; ++kc)
        s += pFB[(size_t)(kc * NB + b) * ND + d];
      sbase[dd] = s;
    }
    __syncthreads();
    const int dd16 = tid >> 4;
    const int r4 = (tid & 15) * 4;
#pragma unroll 4
    for (int i = 0; i < 32; ++i) {
      const int dloc = i * 16 + dd16;
      const int d = dbase + dloc;
      const v4f c = *(const v4f*)(CBT + (size_t)d * NR + r4);
      const v4f v = c + sbase[dloc];
      __builtin_nontemporal_store(v, (v4f*)(outB + ((size_t)bl * ND + d) * NR + r4));
    }
  }
}

extern "C" void kernel_launch(void* const* d_in, const int* in_sizes, int n_in,
                              void* d_out, int out_size, void* d_ws, size_t ws_size,
                              hipStream_t stream) {
  const float* A_small   = (const float*)d_in[0];
  const float* B_small   = (const float*)d_in[1];
  const float* prompt    = (const float*)d_in[2];
  const float* W_ct      = (const float*)d_in[3];
  const float* b_ct      = (const float*)d_in[4];
  const float* W_cp      = (const float*)d_in[5];
  const float* b_cp      = (const float*)d_in[6];
  const float* W_pc      = (const float*)d_in[7];
  const float* b_pc      = (const float*)d_in[8];
  const float* E_layer   = (const float*)d_in[9];
  const float* E_chunk   = (const float*)d_in[10];
  const float* W_A       = (const float*)d_in[11];
  const float* b_A       = (const float*)d_in[12];
  const float* W_B       = (const float*)d_in[13];
  const float* b_B       = (const float*)d_in[14];

  float* ws    = (float*)d_ws;
  float* fused = ws + WS_FUSED;
  float* gatew = ws + WS_GATE;
  float* pLA   = ws + WS_PLA;
  float* pLB   = ws + WS_PLB;
  float* CA    = ws + WS_CA;
  float* CBT   = ws + WS_CBT;
  float* partT = ws + WS_PT;
  float* partP = ws + WS_PP;
  float* pFA   = ws + WS_PFA;
  float* pFB   = ws + WS_PFB;

  float* outA = (float*)d_out;                       // [192,64,4096]
  float* outB = outA + (size_t)192 * NR * ND;        // [192,4096,64]
  float* outG = outB + (size_t)192 * ND * NR;        // [192]

  k_indep<<<736, 256, 0, stream>>>(A_small, B_small, W_ct, prompt, W_cp,
                                   E_layer, E_chunk, W_A, W_B,
                                   partT, partP, pLA, pLB, CA, CBT);
  k_fused_reduce<<<48, 256, 0, stream>>>(partT, partP, b_ct, b_cp, fused);
  k_dep<<<576, 256, 0, stream>>>(fused, W_A, W_B, W_pc, b_pc,
                                 pFA, pFB, gatew, outG);
  k_out<<<3072, 256, 0, stream>>>(pFA, pFB, b_A, b_B, pLA, pLB, CA, CBT,
                                  gatew, outA, outB);
}